// Round 3
// baseline (120.494 us; speedup 1.0000x reference)
//
#include <hip/hip_runtime.h>

// BinsChamferLoss — exact 1-D chamfer via sorted centers + binary search.
// L=4 scales, N=4 batch, P=256 centers (257 edges), M=240*320=76800 y per n.
//
// Direction B (y->centers): j = last sorted-center index with c_j <= y (9-step
//   branchless binary search); min dist = min(y - c_j, c_{j+1} - y).
// Direction A (centers->y): scatter each VALID y into its center-gap interval
//   s = j+1 (atomicMax of bits for "max y below", atomicMin for "min y above";
//   float bits are order-isomorphic to int for y >= 0). Then per (l,n):
//   FL_p = prefix-max over intervals [0..p], FR_p = suffix-min over [p+1..256],
//   minabs_p = min(c_p - FL_p, FR_p - c_p). Exact: every y < c_p lives in an
//   interval <= p, every y >= c_p in an interval >= p+1.
// Squaring AFTER the |.|-min is bitwise-identical to min-of-squares (fp32
// squaring is monotone on |x|).

#define NSCALES 4
#define NBATCH  4
#define NEDGES  257
#define NP      256
#define NM      76800
#define CHUNK   512
#define NCHUNK  (NM / CHUNK)          // 150
#define BLOCK   256
#define NLN     (NSCALES * NBATCH)    // 16
#define NIV     (NP + 1)              // 257 intervals
#define BIGF    1e10f
#define IMIN    ((int)0x80000000)
#define IMAX    0x7fffffff

// ws layout in 4-byte units
#define WS_SORTC 0                        // [16][256] float  sorted centers
#define WS_GA    (WS_SORTC + NLN * NP)    // [16][257] int    max y-bits per interval
#define WS_GB    (WS_GA + NLN * NIV)      // [16][257] int    min y-bits per interval
#define WS_SUMY  (WS_GB + NLN * NIV)      // [16] float       direction-B sums
#define WS_CNT   (WS_SUMY + NLN)          // [4] uint         valid-y counts

__global__ __launch_bounds__(BLOCK) void bcl_prep(const float* __restrict__ bins,
                                                  float* __restrict__ ws) {
    __shared__ float s[NP];
    const int b = blockIdx.x;             // b = l*NBATCH + n
    const int t = threadIdx.x;
    const float* e = bins + b * NEDGES;
    s[t] = 0.5f * (e[t] + e[t + 1]);

    // bitonic sort ascending (256 elements, 1 per thread)
    for (int k = 2; k <= NP; k <<= 1) {
        for (int j = k >> 1; j > 0; j >>= 1) {
            __syncthreads();
            const int ixj = t ^ j;
            const float a = s[t];
            const float c = s[ixj];
            const bool up = ((t & k) == 0);
            float keep;
            if (ixj > t) keep = up ? fminf(a, c) : fmaxf(a, c);
            else         keep = up ? fmaxf(a, c) : fminf(a, c);
            __syncthreads();
            s[t] = keep;
        }
    }
    __syncthreads();
    ws[WS_SORTC + b * NP + t] = s[t];

    int* gA = (int*)ws + WS_GA + b * NIV;
    int* gB = (int*)ws + WS_GB + b * NIV;
    gA[t] = IMIN;
    gB[t] = IMAX;
    if (t == 0) { gA[NP] = IMIN; gB[NP] = IMAX; }
    if (b == 0) {
        if (t < NLN)    ws[WS_SUMY + t] = 0.0f;
        if (t < NBATCH) ((unsigned int*)ws)[WS_CNT + t] = 0u;
    }
}

__global__ __launch_bounds__(BLOCK) void bcl_main(const float* __restrict__ depth,
                                                  float* __restrict__ ws) {
    __shared__ float sC[NSCALES * NP];    // sorted centers, 4 scales of batch n
    __shared__ int sA[NSCALES * NIV];     // block-local scatter max
    __shared__ int sB[NSCALES * NIV];     // block-local scatter min
    __shared__ float redS[BLOCK / 64][NSCALES];
    __shared__ unsigned int redC[BLOCK / 64];

    const int b = blockIdx.x;
    const int n = b / NCHUNK;
    const int chunk = b - n * NCHUNK;
    const int t = threadIdx.x;

#pragma unroll
    for (int l = 0; l < NSCALES; ++l)
        sC[l * NP + t] = ws[WS_SORTC + (l * NBATCH + n) * NP + t];
#pragma unroll
    for (int i = t; i < NSCALES * NIV; i += BLOCK) { sA[i] = IMIN; sB[i] = IMAX; }

    const float* yp = depth + n * NM + chunk * CHUNK;
    const float y0 = yp[t];
    const float y1 = yp[t + BLOCK];
    const bool v0 = (y0 >= 0.001f);
    const bool v1 = (y1 >= 0.001f);

    __syncthreads();

    float suml[NSCALES];
#pragma unroll
    for (int l = 0; l < NSCALES; ++l) suml[l] = 0.0f;

#pragma unroll
    for (int which = 0; which < 2; ++which) {
        const float y = which ? y1 : y0;
        const bool vv = which ? v1 : v0;
        const int yb = __float_as_int(y);
#pragma unroll
        for (int l = 0; l < NSCALES; ++l) {
            const float* c = sC + l * NP;
            // branchless: j = last index with c[j] <= y, in [-1, 255]
            int j = -1;
#pragma unroll
            for (int step = NP; step; step >>= 1) {
                const int cand = j + step;
                const float v = c[cand < NP ? cand : NP - 1];
                j = (cand < NP && v <= y) ? cand : j;
            }
            const float cb = c[j >= 0 ? j : 0];
            const float ca = c[j + 1 < NP ? j + 1 : NP - 1];
            const float dl = (j >= 0)      ? (y - cb) : BIGF;
            const float dr = (j < NP - 1)  ? (ca - y) : BIGF;
            const float d = fminf(dl, dr);
            if (vv) {
                suml[l] += d * d;                      // direction B
                atomicMax(&sA[l * NIV + j + 1], yb);   // direction A scatter
                atomicMin(&sB[l * NIV + j + 1], yb);
            }
        }
    }

    __syncthreads();

    // merge block scatter to global; plain-load pre-check is safe under
    // monotone max/min (stale read <= current => skip is conservative)
    int* gA = (int*)ws + WS_GA;
    int* gB = (int*)ws + WS_GB;
#pragma unroll
    for (int l = 0; l < NSCALES; ++l) {
        const int gbase = (l * NBATCH + n) * NIV;
        for (int k = t; k < NIV; k += BLOCK) {
            const int a = sA[l * NIV + k];
            if (a != IMIN && a > gA[gbase + k]) atomicMax(&gA[gbase + k], a);
            const int bb = sB[l * NIV + k];
            if (bb != IMAX && bb < gB[gbase + k]) atomicMin(&gB[gbase + k], bb);
        }
    }

    // block reduction of direction-B sums + valid count
    unsigned int cc = (v0 ? 1u : 0u) + (v1 ? 1u : 0u);
#pragma unroll
    for (int off = 32; off; off >>= 1) {
#pragma unroll
        for (int l = 0; l < NSCALES; ++l) suml[l] += __shfl_down(suml[l], off);
        cc += __shfl_down(cc, off);
    }
    const int wv = t >> 6;
    if ((t & 63) == 0) {
#pragma unroll
        for (int l = 0; l < NSCALES; ++l) redS[wv][l] = suml[l];
        redC[wv] = cc;
    }
    __syncthreads();
    if (t < NSCALES) {
        const float s2 = redS[0][t] + redS[1][t] + redS[2][t] + redS[3][t];
        atomicAdd(&ws[WS_SUMY + t * NBATCH + n], s2);
    }
    if (t == 0) {
        const unsigned int c4 = redC[0] + redC[1] + redC[2] + redC[3];
        atomicAdd(&((unsigned int*)ws)[WS_CNT + n], c4);
    }
}

__global__ __launch_bounds__(BLOCK) void bcl_final(const float* __restrict__ wsf,
                                                   float* __restrict__ out) {
    __shared__ int lA[NLN * NIV];
    __shared__ int lB[NLN * NIV];
    __shared__ float red[BLOCK / 64];
    const int t = threadIdx.x;
    const int* gA = (const int*)wsf + WS_GA;
    const int* gB = (const int*)wsf + WS_GB;
    for (int i = t; i < NLN * NIV; i += BLOCK) { lA[i] = gA[i]; lB[i] = gB[i]; }
    __syncthreads();

    // 16 serial scans: FL (prefix-max, in place at slot p) and FR (suffix-min,
    // in place at slot p+1)
    if (t < NLN) {
        const int base = t * NIV;
        int run = IMIN;
        for (int k = 0; k < NP; ++k) { run = max(run, lA[base + k]); lA[base + k] = run; }
        int run2 = IMAX;
        for (int p = NP - 1; p >= 0; --p) { run2 = min(run2, lB[base + p + 1]); lB[base + p + 1] = run2; }
    }
    __syncthreads();

    float tot = 0.0f;
#pragma unroll
    for (int ln = 0; ln < NLN; ++ln) {
        const float c = wsf[WS_SORTC + ln * NP + t];
        const int fl = lA[ln * NIV + t];
        const int fr = lB[ln * NIV + t + 1];
        const float dl = (fl == IMIN) ? BIGF : (c - __int_as_float(fl));
        const float dr = (fr == IMAX) ? BIGF : (__int_as_float(fr) - c);
        const float m = fminf(dl, dr);
        tot += m * m;                      // direction A accumulation
    }
#pragma unroll
    for (int off = 32; off; off >>= 1) tot += __shfl_down(tot, off);
    if ((t & 63) == 0) red[t >> 6] = tot;
    __syncthreads();
    if (t == 0) {
        const float S = red[0] + red[1] + red[2] + red[3];
        float lossB = 0.0f;
#pragma unroll
        for (int i = 0; i < NLN; ++i)
            lossB += wsf[WS_SUMY + i] /
                     (float)((const unsigned int*)wsf)[WS_CNT + (i & (NBATCH - 1))];
        out[0] = (S / (float)NP + lossB) / (float)NBATCH;
    }
}

extern "C" void kernel_launch(void* const* d_in, const int* in_sizes, int n_in,
                              void* d_out, int out_size, void* d_ws, size_t ws_size,
                              hipStream_t stream) {
    const float* bins  = (const float*)d_in[0];   // [4,4,257] f32
    const float* depth = (const float*)d_in[1];   // [4,240,320] f32
    float* ws = (float*)d_ws;

    bcl_prep <<<NLN,           BLOCK, 0, stream>>>(bins, ws);
    bcl_main <<<NBATCH*NCHUNK, BLOCK, 0, stream>>>(depth, ws);
    bcl_final<<<1,             BLOCK, 0, stream>>>(ws, (float*)d_out);
}

// Round 4
// 105.347 us; speedup vs baseline: 1.1438x; 1.1438x over previous
//
#include <hip/hip_runtime.h>

// BinsChamferLoss — regular brute-force chamfer (round-1 structure), tuned.
// L=4 scales, N=4 batch, P=256 centers, M=76800 y per batch element.
//
// Round-3 lesson (counters): binary-search + LDS-atomic scatter was
// latency-bound (VALUBusy 3.8%, 1.44M LDS bank-conflict cycles, dependent
// divergent LDS chains, skewed same-address ds_max serialization). The
// broadcast-LDS brute force is issue-bound — keep it, and cut issue count:
//   - v_min3_f32 fusion: fminf(fminf(m,|c-y0|),|c-y1|) = 2 sub + 1 min3
//     per 2 pairs (abs = free VOP3 input modifier) -> 1.5 VALU/pair.
//   - CHUNK=256 -> 1200 blocks -> ~4.7 waves/SIMD (was 2.3).
//   - pre-filtered global atomicMin (monotone => stale-read skip is safe).
// Squaring after the |.|-min is bitwise-identical to min-of-squares (fp32
// squaring is monotone on |x|, RN is monotone).

#define NSCALES 4
#define NBATCH  4
#define NEDGES  257
#define NP      256
#define NM      76800
#define CHUNK   256
#define NCHUNK  (NM / CHUNK)          // 300
#define BLOCK   256
#define NLN     (NSCALES * NBATCH)    // 16
#define BIGF    1e10f

__global__ __launch_bounds__(BLOCK) void bcl_init(float* __restrict__ minabs,
                                                  float* __restrict__ sumy,
                                                  unsigned int* __restrict__ cnt) {
    const int t = blockIdx.x * BLOCK + threadIdx.x;
    if (t < NLN * NP) minabs[t] = BIGF;
    if (t < NLN)      sumy[t]   = 0.0f;
    if (t < NBATCH)   cnt[t]    = 0u;
}

__global__ __launch_bounds__(BLOCK) void bcl_main(const float* __restrict__ bins,
                                                  const float* __restrict__ depth,
                                                  float* __restrict__ minabs,
                                                  float* __restrict__ sumy,
                                                  unsigned int* __restrict__ cnt) {
    __shared__ float sY[CHUNK];           // y chunk (invalid -> 3e9 sentinel)
    __shared__ float sC[NSCALES * NP];    // centers, all 4 scales of batch n
    __shared__ float redS[BLOCK / 64][NSCALES];
    __shared__ unsigned int redC[BLOCK / 64];

    const int b = blockIdx.x;
    const int n = b / NCHUNK;
    const int chunk = b - n * NCHUNK;
    const int t = threadIdx.x;

    // --- stage y (1 per thread) and centers (4 per thread) ---
    {
        const float v = depth[n * NM + chunk * CHUNK + t];
        sY[t] = (v >= 0.001f) ? v : 3e9f;
    }
#pragma unroll
    for (int k = 0; k < 4; ++k) {
        const int i = t + k * BLOCK;
        const int l = i >> 8;
        const int p = i & (NP - 1);
        const float* e = bins + (l * NBATCH + n) * NEDGES + p;
        sC[i] = 0.5f * (e[0] + e[1]);
    }
    __syncthreads();

    // ============ direction A: per-center min over y chunk ============
    // thread t owns center p=t of each scale l (broadcast sY reads)
    float ca[NSCALES], ma[NSCALES];
#pragma unroll
    for (int l = 0; l < NSCALES; ++l) { ca[l] = sC[t + (l << 8)]; ma[l] = BIGF; }

    const float4* sY4 = (const float4*)sY;
#pragma unroll 4
    for (int q = 0; q < CHUNK / 4; ++q) {
        const float4 y4 = sY4[q];
#pragma unroll
        for (int l = 0; l < NSCALES; ++l) {
            ma[l] = fminf(fminf(ma[l], fabsf(ca[l] - y4.x)), fabsf(ca[l] - y4.y));
            ma[l] = fminf(fminf(ma[l], fabsf(ca[l] - y4.z)), fabsf(ca[l] - y4.w));
        }
    }
    // pre-filtered global merge; int-compare == float-compare for y >= 0
#pragma unroll
    for (int l = 0; l < NSCALES; ++l) {
        const int idx = (l * NBATCH + n) * NP + t;
        if (ma[l] < minabs[idx])
            atomicMin((int*)(minabs + idx), __float_as_int(ma[l]));
    }

    // ============ direction B: per-y min over all 1024 centers ============
    const float y = sY[t];
    const bool valid = (y < 2.0f);        // sentinel = 3e9

    float suml[NSCALES];
    const float4* sC4 = (const float4*)sC;
#pragma unroll
    for (int l = 0; l < NSCALES; ++l) {
        float m = BIGF;
#pragma unroll 4
        for (int q = 0; q < NP / 4; ++q) {
            const float4 c = sC4[(l << 6) + q];
            m = fminf(fminf(m, fabsf(c.x - y)), fabsf(c.y - y));
            m = fminf(fminf(m, fabsf(c.z - y)), fabsf(c.w - y));
        }
        suml[l] = valid ? m * m : 0.0f;
    }
    unsigned int cc = valid ? 1u : 0u;

    // --- block reduction (wave shuffle + LDS across 4 waves) ---
#pragma unroll
    for (int off = 32; off; off >>= 1) {
#pragma unroll
        for (int l = 0; l < NSCALES; ++l) suml[l] += __shfl_down(suml[l], off);
        cc += __shfl_down(cc, off);
    }
    const int wv = t >> 6;
    if ((t & 63) == 0) {
#pragma unroll
        for (int l = 0; l < NSCALES; ++l) redS[wv][l] = suml[l];
        redC[wv] = cc;
    }
    __syncthreads();
    if (t < NSCALES) {
        const float s = redS[0][t] + redS[1][t] + redS[2][t] + redS[3][t];
        atomicAdd(&sumy[t * NBATCH + n], s);
    }
    if (t == 0) {
        const unsigned int c4 = redC[0] + redC[1] + redC[2] + redC[3];
        atomicAdd(&cnt[n], c4);
    }
}

__global__ __launch_bounds__(BLOCK) void bcl_final(const float* __restrict__ minabs,
                                                   const float* __restrict__ sumy,
                                                   const unsigned int* __restrict__ cnt,
                                                   float* __restrict__ out) {
    __shared__ float red[BLOCK / 64];
    const int t = threadIdx.x;
    float s = 0.0f;
#pragma unroll
    for (int k = 0; k < (NLN * NP) / BLOCK; ++k) {
        const float m = minabs[t + k * BLOCK];
        s += m * m;
    }
#pragma unroll
    for (int off = 32; off; off >>= 1) s += __shfl_down(s, off);
    if ((t & 63) == 0) red[t >> 6] = s;
    __syncthreads();
    if (t == 0) {
        const float S = red[0] + red[1] + red[2] + red[3];   // sum of minx^2
        float lossB = 0.0f;
#pragma unroll
        for (int i = 0; i < NLN; ++i)
            lossB += sumy[i] / (float)cnt[i & (NBATCH - 1)];
        out[0] = (S / (float)NP + lossB) / (float)NBATCH;
    }
}

extern "C" void kernel_launch(void* const* d_in, const int* in_sizes, int n_in,
                              void* d_out, int out_size, void* d_ws, size_t ws_size,
                              hipStream_t stream) {
    const float* bins  = (const float*)d_in[0];   // [4,4,257] f32
    const float* depth = (const float*)d_in[1];   // [4,240,320] f32

    float* minabs = (float*)d_ws;                              // 16*256 floats
    float* sumy   = minabs + NLN * NP;                         // 16 floats
    unsigned int* cnt = (unsigned int*)(sumy + NLN);           // 4 uints

    bcl_init <<<NLN * NP / BLOCK, BLOCK, 0, stream>>>(minabs, sumy, cnt);
    bcl_main <<<NBATCH * NCHUNK,  BLOCK, 0, stream>>>(bins, depth, minabs, sumy, cnt);
    bcl_final<<<1,                BLOCK, 0, stream>>>(minabs, sumy, cnt, (float*)d_out);
}

// Round 6
// 105.122 us; speedup vs baseline: 1.1462x; 1.0021x over previous
//
#include <hip/hip_runtime.h>

// BinsChamferLoss — brute-force chamfer with SCALAR-PIPE operand streaming.
// L=4 scales, N=4 batch, P=256 centers, M=76800 y per batch element.
//
// Round-4 counters: VALUBusy 43%, 57% stall with 0 bank conflicts — the
// broadcast LDS reads (one shared LDS pipe per CU, 4 SIMDs contending) plus
// dependent-load waitcnt dominate. Fix: the streamed operand of each phase is
// wave-uniform -> load it through the SCALAR pipe (s_load_dwordx16) into
// SGPRs; VALU reads the SGPR as src0 (legal: 1 SGPR read per vector instr).
// For the compiler to emit s_load it must see readonly + uniform: stream
// operands come in via separate const __restrict__ pointers to DISJOINT ws
// regions (aliasing a written pointer would block scalar promotion).
// Private operands (own 4 centers / own y) live in VGPRs. Zero LDS in the
// hot loop. Prep pass materializes centers and sentineled y so the inner
// loop is pure v_sub + v_min (abs = free VOP3 input modifier, min3-fusable).
//
// Squaring after the |.|-min is bitwise-identical to min-of-squares (fp32
// squaring and RN rounding are monotone on |x|).

#define NSCALES 4
#define NBATCH  4
#define NEDGES  257
#define NP      256
#define NM      76800
#define CHUNK   256
#define NCHUNK  (NM / CHUNK)          // 300
#define BLOCK   256
#define NLN     (NSCALES * NBATCH)    // 16
#define BIGF    1e10f
#define SENT    3e9f

// ws layout in floats (16B-aligned sections, mutually disjoint)
#define WS_MIN   0                    // [16*256] minabs  (rw)
#define WS_SUMY  4096                 // [16]             (rw)
#define WS_CNT   4112                 // [4] uint         (rw)
#define WS_CENT  4352                 // [16*256] centers (ro in main)
#define WS_Y     8448                 // [4*76800] y      (ro in main)

__global__ __launch_bounds__(BLOCK) void bcl_prep(const float* __restrict__ bins,
                                                  const float* __restrict__ depth,
                                                  float* __restrict__ ws) {
    const int b = blockIdx.x;
    const int t = threadIdx.x;
    if (b < NLN) {
        // centers for (l,n) = b, plus small-state init
        const float* e = bins + b * NEDGES;
        ws[WS_CENT + b * NP + t] = 0.5f * (e[t] + e[t + 1]);
        ws[WS_MIN + b * NP + t] = BIGF;
        if (b == 0) {
            if (t < NLN)    ws[WS_SUMY + t] = 0.0f;
            if (t < NBATCH) ((unsigned int*)ws)[WS_CNT + t] = 0u;
        }
    } else {
        // sentinel pass: 1024 y per block, float4 per thread
        const int base = (b - NLN) * 1024 + t * 4;
        float4 v = *(const float4*)(depth + base);
        v.x = (v.x >= 0.001f) ? v.x : SENT;
        v.y = (v.y >= 0.001f) ? v.y : SENT;
        v.z = (v.z >= 0.001f) ? v.z : SENT;
        v.w = (v.w >= 0.001f) ? v.w : SENT;
        *(float4*)(ws + WS_Y + base) = v;
    }
}

__global__ __launch_bounds__(BLOCK) void bcl_main(const float* __restrict__ cent,
                                                  const float* __restrict__ yarr,
                                                  float* __restrict__ minabs,
                                                  float* __restrict__ sumy,
                                                  unsigned int* __restrict__ cnt) {
    __shared__ float redS[BLOCK / 64][NSCALES];
    __shared__ unsigned int redC[BLOCK / 64];

    const int b = blockIdx.x;
    const int n = b / NCHUNK;
    const int chunk = b - n * NCHUNK;
    const int t = threadIdx.x;

    // private operands (VGPR)
    float ca[NSCALES];                       // own center p=t of each scale
#pragma unroll
    for (int l = 0; l < NSCALES; ++l)
        ca[l] = cent[(l * NBATCH + n) * NP + t];
    const float yv = yarr[n * NM + chunk * CHUNK + t];   // own y
    const bool valid = (yv < 2.0f);

    // ---- phase A: stream this chunk's 256 y through SGPRs; min into ma[l] ----
    const float* __restrict__ ystream = yarr + n * NM + chunk * CHUNK;
    float ma[NSCALES];
#pragma unroll
    for (int l = 0; l < NSCALES; ++l) ma[l] = BIGF;

#pragma unroll 2
    for (int w = 0; w < CHUNK / 16; ++w) {   // 16 scalar-window iterations
        float yw[16];
#pragma unroll
        for (int j = 0; j < 16; ++j) yw[j] = ystream[w * 16 + j];  // uniform+ro -> s_load
#pragma unroll
        for (int j = 0; j < 16; j += 2) {
#pragma unroll
            for (int l = 0; l < NSCALES; ++l) {
                const float d0 = ca[l] - yw[j];
                const float d1 = ca[l] - yw[j + 1];
                ma[l] = fminf(fminf(ma[l], fabsf(d0)), fabsf(d1));
            }
        }
    }
    // pre-filtered global merge (monotone min => stale-read skip is safe);
    // int compare == float compare for non-negative floats
#pragma unroll
    for (int l = 0; l < NSCALES; ++l) {
        const int idx = (l * NBATCH + n) * NP + t;
        if (ma[l] < minabs[idx])
            atomicMin((int*)minabs + idx, __float_as_int(ma[l]));
    }

    // ---- phase B: stream all 1024 centers through SGPRs; min per scale ----
    float suml[NSCALES];
#pragma unroll
    for (int l = 0; l < NSCALES; ++l) {
        const float* __restrict__ cstream = cent + (l * NBATCH + n) * NP;
        float m0 = BIGF, m1 = BIGF;          // two chains for ILP
#pragma unroll 2
        for (int w = 0; w < NP / 16; ++w) {
            float cw[16];
#pragma unroll
            for (int j = 0; j < 16; ++j) cw[j] = cstream[w * 16 + j];  // uniform+ro -> s_load
#pragma unroll
            for (int j = 0; j < 16; j += 4) {
                const float d0 = cw[j]     - yv;
                const float d1 = cw[j + 1] - yv;
                const float d2 = cw[j + 2] - yv;
                const float d3 = cw[j + 3] - yv;
                m0 = fminf(fminf(m0, fabsf(d0)), fabsf(d1));
                m1 = fminf(fminf(m1, fabsf(d2)), fabsf(d3));
            }
        }
        const float m = fminf(m0, m1);
        suml[l] = valid ? m * m : 0.0f;
    }
    unsigned int cc = valid ? 1u : 0u;

    // ---- block reduction (wave shuffle + LDS across 4 waves) ----
#pragma unroll
    for (int off = 32; off; off >>= 1) {
#pragma unroll
        for (int l = 0; l < NSCALES; ++l) suml[l] += __shfl_down(suml[l], off);
        cc += __shfl_down(cc, off);
    }
    const int wv = t >> 6;
    if ((t & 63) == 0) {
#pragma unroll
        for (int l = 0; l < NSCALES; ++l) redS[wv][l] = suml[l];
        redC[wv] = cc;
    }
    __syncthreads();
    if (t < NSCALES) {
        const float s = redS[0][t] + redS[1][t] + redS[2][t] + redS[3][t];
        atomicAdd(&sumy[t * NBATCH + n], s);
    }
    if (t == 0) {
        const unsigned int c4 = redC[0] + redC[1] + redC[2] + redC[3];
        atomicAdd(&cnt[n], c4);
    }
}

__global__ __launch_bounds__(BLOCK) void bcl_final(const float* __restrict__ ws,
                                                   float* __restrict__ out) {
    __shared__ float red[BLOCK / 64];
    const int t = threadIdx.x;
    float s = 0.0f;
#pragma unroll
    for (int k = 0; k < NLN; ++k) {
        const float m = ws[WS_MIN + t + k * BLOCK];
        s += m * m;
    }
#pragma unroll
    for (int off = 32; off; off >>= 1) s += __shfl_down(s, off);
    if ((t & 63) == 0) red[t >> 6] = s;
    __syncthreads();
    if (t == 0) {
        const float S = red[0] + red[1] + red[2] + red[3];   // sum of minx^2
        float lossB = 0.0f;
#pragma unroll
        for (int i = 0; i < NLN; ++i)
            lossB += ws[WS_SUMY + i] /
                     (float)((const unsigned int*)ws)[WS_CNT + (i & (NBATCH - 1))];
        out[0] = (S / (float)NP + lossB) / (float)NBATCH;
    }
}

extern "C" void kernel_launch(void* const* d_in, const int* in_sizes, int n_in,
                              void* d_out, int out_size, void* d_ws, size_t ws_size,
                              hipStream_t stream) {
    const float* bins  = (const float*)d_in[0];   // [4,4,257] f32
    const float* depth = (const float*)d_in[1];   // [4,240,320] f32
    float* ws = (float*)d_ws;

    bcl_prep <<<NLN + NM * NBATCH / 1024, BLOCK, 0, stream>>>(bins, depth, ws);
    bcl_main <<<NBATCH * NCHUNK, BLOCK, 0, stream>>>(
        ws + WS_CENT, ws + WS_Y, ws + WS_MIN, ws + WS_SUMY,
        (unsigned int*)ws + WS_CNT);
    bcl_final<<<1, BLOCK, 0, stream>>>(ws, (float*)d_out);
}